// Round 19
// baseline (101.617 us; speedup 1.0000x reference)
//
#include <hip/hip_runtime.h>
#include <hip/hip_bf16.h>
#include <stdint.h>

// Problem constants
constexpr int B    = 8;
constexpr int T    = 2048;
constexpr int EMB  = 2048;
constexpr int HD   = 128;
constexpr int M    = B * T;        // 16384 rows for projection GEMM
constexpr int NW   = 3 * HD;       // 384 fused output cols (Q|K|V)

typedef __attribute__((ext_vector_type(8))) short short8;
typedef __attribute__((ext_vector_type(4))) float f32x4;

__device__ inline unsigned short f2bf(float f) {
    union { float f; unsigned int u; } v; v.f = f;
    unsigned int x = v.u;
    unsigned int r = (x + 0x7FFFu + ((x >> 16) & 1u)) >> 16;   // RNE
    return (unsigned short)r;
}

__device__ inline float bf2f(unsigned short s) {
    union { unsigned int u; float f; } v; v.u = ((unsigned int)s) << 16;
    return v.f;
}

__device__ inline unsigned int cvt_pk_bf16(float a, float b) {
    unsigned int r;
    asm volatile("v_cvt_pk_bf16_f32 %0, %1, %2" : "=v"(r) : "v"(a), "v"(b));
    return r;   // lo = bf16(a), hi = bf16(b)
}

// ---------------------------------------------------------------------------
// Kernel 0: convert Wq|Wk|Wv fp32 -> bf16 into Wb[384][2048]
// ---------------------------------------------------------------------------
__global__ __launch_bounds__(256) void conv_w(
    const float* __restrict__ Wq, const float* __restrict__ Wk, const float* __restrict__ Wv,
    unsigned short* __restrict__ Wb)
{
    int base = (blockIdx.x * 256 + threadIdx.x) * 8;   // < 384*2048
    int row = base >> 11, col = base & 2047;
    const float* src;
    if (row < 128)      src = Wq + (size_t)row * EMB + col;
    else if (row < 256) src = Wk + (size_t)(row - 128) * EMB + col;
    else                src = Wv + (size_t)(row - 256) * EMB + col;
    float4 a = *(const float4*)src;
    float4 b = *(const float4*)(src + 4);
    short8 sv;
    sv[0] = f2bf(a.x); sv[1] = f2bf(a.y); sv[2] = f2bf(a.z); sv[3] = f2bf(a.w);
    sv[4] = f2bf(b.x); sv[5] = f2bf(b.y); sv[6] = f2bf(b.z); sv[7] = f2bf(b.w);
    *(short8*)(Wb + base) = sv;
}

// ---------------------------------------------------------------------------
// Kernel 1: fused QKV projection — R18 config + 2-DEEP register prefetch.
// At iteration t: issue loads for tile t+2 into the E/O reg set freed last
// iteration; writeTile(t+1) consumes registers loaded a FULL iteration
// (~2800cy) earlier -> x's ~900cy HBM latency fully covered (was only
// ~400-600cy of compute). Named even/odd sets (rule 20), hand-unrolled x2.
// All else identical to R18 (BN=192, 2 blocks/CU, XOR swizzles, K-stagger).
// ---------------------------------------------------------------------------
constexpr int PBM = 64;
constexpr int PBN = 192;
constexpr int PBK = 64;
constexpr int PNT = EMB / PBK;   // 32

__global__ __launch_bounds__(256, 2) void qkv_proj(
    const float* __restrict__ x, const unsigned short* __restrict__ Wb,
    unsigned short* __restrict__ Qb, unsigned short* __restrict__ Kb,
    unsigned short* __restrict__ VtG)
{
    __shared__ unsigned short Ab[2][PBM * PBK];   // 2 x 8 KB
    __shared__ unsigned short Bb[2][PBN * PBK];   // 2 x 24 KB  (64 KB total)

    const int d   = blockIdx.x;          // 0..511
    const int xcd = d & 7;
    const int g   = d >> 3;              // 0..63
    const int mt  = xcd * 32 + (g >> 1); // 0..255
    const int ns  = g & 1;               // N-half
    const int m0  = mt * PBM;
    const int n0  = ns * PBN;
    const int phase = g & 31;            // staggered K start per in-XCD block

    const int tid  = threadIdx.x;
    const int lane = tid & 63;
    const int w    = tid >> 6;           // 0..3
    const int lo   = lane & 15;
    const int hi   = lane >> 4;

    const int ar = tid >> 2;             // 0..63
    const int s0 = (tid & 3) * 2;        // first 8-float seg (0,2,4,6)
    const float* asrc = x + (size_t)(m0 + ar) * EMB + s0 * 8;

    f32x4 acc[4][3];
#pragma unroll
    for (int i = 0; i < 4; ++i)
#pragma unroll
        for (int j = 0; j < 3; ++j) acc[i][j] = (f32x4)0.0f;

    // even/odd register sets (rule 20: all statically named)
    short8 bregE[6], bregO[6];
    float4 aE0, aE1, aE2, aE3, aO0, aO1, aO2, aO3;

    auto ktile = [&](int t) { return ((phase + t) & 31) * PBK; };

    auto loadE = [&](int k0) {
#pragma unroll
        for (int it = 0; it < 6; ++it) {
            int c = it * 256 + tid;
            bregE[it] = *(const short8*)(Wb + (size_t)(n0 + (c >> 3)) * EMB + k0 + (c & 7) * 8);
        }
        aE0 = *(const float4*)(asrc + k0);
        aE1 = *(const float4*)(asrc + k0 + 4);
        aE2 = *(const float4*)(asrc + k0 + 8);
        aE3 = *(const float4*)(asrc + k0 + 12);
    };
    auto loadO = [&](int k0) {
#pragma unroll
        for (int it = 0; it < 6; ++it) {
            int c = it * 256 + tid;
            bregO[it] = *(const short8*)(Wb + (size_t)(n0 + (c >> 3)) * EMB + k0 + (c & 7) * 8);
        }
        aO0 = *(const float4*)(asrc + k0);
        aO1 = *(const float4*)(asrc + k0 + 4);
        aO2 = *(const float4*)(asrc + k0 + 8);
        aO3 = *(const float4*)(asrc + k0 + 12);
    };
    auto writeE = [&](int buf) {
#pragma unroll
        for (int it = 0; it < 6; ++it) {
            int c = it * 256 + tid;
            int row = c >> 3, seg = c & 7;
            *(short8*)&Bb[buf][row * PBK + (seg ^ (row & 7)) * 8] = bregE[it];
        }
        uint4 p0, p1;
        p0.x = cvt_pk_bf16(aE0.x, aE0.y);  p0.y = cvt_pk_bf16(aE0.z, aE0.w);
        p0.z = cvt_pk_bf16(aE1.x, aE1.y);  p0.w = cvt_pk_bf16(aE1.z, aE1.w);
        p1.x = cvt_pk_bf16(aE2.x, aE2.y);  p1.y = cvt_pk_bf16(aE2.z, aE2.w);
        p1.z = cvt_pk_bf16(aE3.x, aE3.y);  p1.w = cvt_pk_bf16(aE3.z, aE3.w);
        *(uint4*)&Ab[buf][ar * PBK + ((s0    ) ^ (ar & 7)) * 8] = p0;
        *(uint4*)&Ab[buf][ar * PBK + ((s0 + 1) ^ (ar & 7)) * 8] = p1;
    };
    auto writeO = [&](int buf) {
#pragma unroll
        for (int it = 0; it < 6; ++it) {
            int c = it * 256 + tid;
            int row = c >> 3, seg = c & 7;
            *(short8*)&Bb[buf][row * PBK + (seg ^ (row & 7)) * 8] = bregO[it];
        }
        uint4 p0, p1;
        p0.x = cvt_pk_bf16(aO0.x, aO0.y);  p0.y = cvt_pk_bf16(aO0.z, aO0.w);
        p0.z = cvt_pk_bf16(aO1.x, aO1.y);  p0.w = cvt_pk_bf16(aO1.z, aO1.w);
        p1.x = cvt_pk_bf16(aO2.x, aO2.y);  p1.y = cvt_pk_bf16(aO2.z, aO2.w);
        p1.z = cvt_pk_bf16(aO3.x, aO3.y);  p1.w = cvt_pk_bf16(aO3.z, aO3.w);
        *(uint4*)&Ab[buf][ar * PBK + ((s0    ) ^ (ar & 7)) * 8] = p0;
        *(uint4*)&Ab[buf][ar * PBK + ((s0 + 1) ^ (ar & 7)) * 8] = p1;
    };
    auto compute = [&](int buf) {
#pragma unroll
        for (int kk = 0; kk < 2; ++kk) {
            short8 af[4], bf[3];
            const int cseg = kk * 4 + hi;
#pragma unroll
            for (int i = 0; i < 4; ++i) {
                int R = i * 16 + lo;
                af[i] = *(const short8*)&Ab[buf][R * PBK + (cseg ^ (R & 7)) * 8];
            }
#pragma unroll
            for (int j = 0; j < 3; ++j) {
                int n = w * 48 + j * 16 + lo;     // local col in 192
                bf[j] = *(const short8*)&Bb[buf][n * PBK + (cseg ^ (n & 7)) * 8];
            }
#pragma unroll
            for (int i = 0; i < 4; ++i)
#pragma unroll
                for (int j = 0; j < 3; ++j)
                    acc[i][j] = __builtin_amdgcn_mfma_f32_16x16x32_bf16(af[i], bf[j], acc[i][j], 0, 0, 0);
        }
    };

    // prologue: E=tile0, O=tile1; write tile0 into buf0
    loadE(ktile(0));
    loadO(ktile(1));
    writeE(0);
    __syncthreads();

#pragma unroll 1
    for (int tt = 0; tt < PNT; tt += 2) {
        // ---- even iteration t=tt (buf 0); E set free -> load tile tt+2 ----
        if (tt + 2 < PNT) loadE(ktile(tt + 2));
        __builtin_amdgcn_sched_barrier(0);
        compute(0);
        __builtin_amdgcn_sched_barrier(0);
        writeO(1);                       // tile tt+1: regs landed long ago
        __syncthreads();
        // ---- odd iteration t=tt+1 (buf 1); O set free -> load tile tt+3 ----
        if (tt + 3 < PNT) loadO(ktile(tt + 3));
        __builtin_amdgcn_sched_barrier(0);
        compute(1);
        if (tt + 2 < PNT) {
            __builtin_amdgcn_sched_barrier(0);
            writeE(0);                   // tile tt+2
            __syncthreads();
        }
    }

    // epilogue. C layout: row = hi*4+r, col = lo.
    const int b = m0 >> 11;
#pragma unroll
    for (int i = 0; i < 4; ++i) {
        int mrow0 = m0 + i * 16 + hi * 4;
#pragma unroll
        for (int j = 0; j < 3; ++j) {
            int colbase = n0 + w * 48 + j * 16 + lo;   // 0..383
            if (colbase < 128) {               // Q
#pragma unroll
                for (int r = 0; r < 4; ++r)
                    Qb[(size_t)(mrow0 + r) * HD + colbase] = f2bf(acc[i][j][r]);
            } else if (colbase < 256) {        // K
#pragma unroll
                for (int r = 0; r < 4; ++r)
                    Kb[(size_t)(mrow0 + r) * HD + (colbase - 128)] = f2bf(acc[i][j][r]);
            } else {                           // V -> transposed [B][HD][T]
                int h = colbase - 256;
                int tloc = mrow0 - b * T;
                ushort4 pv;
                pv.x = f2bf(acc[i][j][0]); pv.y = f2bf(acc[i][j][1]);
                pv.z = f2bf(acc[i][j][2]); pv.w = f2bf(acc[i][j][3]);
                *(ushort4*)(VtG + ((size_t)(b * HD + h)) * T + tloc) = pv;
            }
        }
    }
}

// ---------------------------------------------------------------------------
// Kernel 2: causal flash attention with KV-split (R18 config, bf16 partials).
// ---------------------------------------------------------------------------
constexpr int QB = 64;
constexpr int KB = 64;
constexpr int STILES = 8;   // kv tiles per split block

__global__ __launch_bounds__(256) void attn_fwd(
    const unsigned short* __restrict__ Qb,
    const unsigned short* __restrict__ Kb,
    const unsigned short* __restrict__ VtG,
    float* __restrict__ out,
    unsigned short* __restrict__ part_o, float* __restrict__ part_ml,
    int use_split)
{
    const int b  = blockIdx.y;
    int bx = blockIdx.x;
    int qt, s, nsplit;
    if (use_split) {
        if (bx < 8)       { qt = bx;               s = 0; }
        else if (bx < 24) { qt = 8  + (bx - 8) / 2;  s = (bx - 8) & 1; }
        else if (bx < 48) { qt = 16 + (bx - 24) / 3; s = (bx - 24) % 3; }
        else              { qt = 24 + (bx - 48) / 4; s = (bx - 48) & 3; }
        nsplit = qt / 8 + 1;
    } else {
        qt = bx; s = 0; nsplit = 1;
    }
    const int q0 = qt * QB;
    int t0 = s * STILES;
    int t1 = t0 + STILES; if (t1 > qt + 1) t1 = qt + 1;

    const int tid  = threadIdx.x;
    const int lane = tid & 63;
    const int w    = tid >> 6;
    const int lo   = lane & 15;
    const int hi   = lane >> 4;

    __shared__ unsigned short Ks[KB][HD + 8];    // stride 272B == 4 banks mod 32
    __shared__ unsigned short Vt[HD][KB + 16];   // stride 160B == 8 banks mod 32
    __shared__ unsigned short Ps[QB][KB + 8];

    short8 qf[4];
    {
        int row = q0 + w * 16 + lo;
        const unsigned short* qp = Qb + ((size_t)b * T + row) * HD + hi * 8;
#pragma unroll
        for (int ks = 0; ks < 4; ++ks) qf[ks] = *(const short8*)(qp + ks * 32);
    }

    float mrow[4], lrow[4];
    f32x4 o[8];
#pragma unroll
    for (int r = 0; r < 4; ++r) { mrow[r] = -1e30f; lrow[r] = 0.0f; }
#pragma unroll
    for (int n = 0; n < 8; ++n) o[n] = (f32x4)0.0f;

    const float scale2 = 0.022097086912079608f * 1.4426950408889634f;
    const int qrow_base = q0 + w * 16 + hi * 4;

    for (int t = t0; t < t1; ++t) {
        const int kv0 = t * KB;
#pragma unroll
        for (int it = 0; it < 4; ++it) {
            int c = tid + it * 256;
            int row = c >> 4, c8 = (c & 15) * 8;
            *(short8*)&Ks[row][c8] =
                *(const short8*)(Kb + ((size_t)b * T + kv0 + row) * HD + c8);
        }
#pragma unroll
        for (int it = 0; it < 4; ++it) {
            int c = tid + it * 256;
            int row = c >> 3, c8 = (c & 7) * 8;
            *(short8*)&Vt[row][c8] =
                *(const short8*)(VtG + (size_t)(b * HD + row) * T + kv0 + c8);
        }
        __syncthreads();

        f32x4 sa[4];
#pragma unroll
        for (int j = 0; j < 4; ++j) sa[j] = (f32x4)0.0f;
#pragma unroll
        for (int ks = 0; ks < 4; ++ks) {
#pragma unroll
            for (int j = 0; j < 4; ++j) {
                short8 bf = *(const short8*)&Ks[j * 16 + lo][ks * 32 + hi * 8];
                sa[j] = __builtin_amdgcn_mfma_f32_16x16x32_bf16(qf[ks], bf, sa[j], 0, 0, 0);
            }
        }

        const bool diag = (t == qt);
        float alpha[4];
#pragma unroll
        for (int r = 0; r < 4; ++r) {
            const int qrow = qrow_base + r;
            float rm = -1e30f;
#pragma unroll
            for (int j = 0; j < 4; ++j) {
                float v = sa[j][r] * scale2;
                if (diag) {
                    int kv = kv0 + j * 16 + lo;
                    v = (kv <= qrow) ? v : -1e30f;
                }
                sa[j][r] = v;
                rm = fmaxf(rm, v);
            }
            rm = fmaxf(rm, __shfl_xor(rm, 1));
            rm = fmaxf(rm, __shfl_xor(rm, 2));
            rm = fmaxf(rm, __shfl_xor(rm, 4));
            rm = fmaxf(rm, __shfl_xor(rm, 8));
            float mn = fmaxf(mrow[r], rm);
            alpha[r] = exp2f(mrow[r] - mn);
            mrow[r] = mn;
            float ls = 0.0f;
#pragma unroll
            for (int j = 0; j < 4; ++j) {
                float p = exp2f(sa[j][r] - mn);
                sa[j][r] = p;
                ls += p;
            }
            ls += __shfl_xor(ls, 1);
            ls += __shfl_xor(ls, 2);
            ls += __shfl_xor(ls, 4);
            ls += __shfl_xor(ls, 8);
            lrow[r] = lrow[r] * alpha[r] + ls;
        }
#pragma unroll
        for (int n = 0; n < 8; ++n)
#pragma unroll
            for (int r = 0; r < 4; ++r) o[n][r] *= alpha[r];

#pragma unroll
        for (int r = 0; r < 4; ++r)
#pragma unroll
            for (int j = 0; j < 4; ++j)
                Ps[w * 16 + hi * 4 + r][j * 16 + lo] = f2bf(sa[j][r]);
        __syncthreads();

#pragma unroll
        for (int ks = 0; ks < 2; ++ks) {
            short8 af = *(const short8*)&Ps[w * 16 + lo][ks * 32 + hi * 8];
#pragma unroll
            for (int n = 0; n < 8; ++n) {
                short8 bv = *(const short8*)&Vt[n * 16 + lo][ks * 32 + hi * 8];
                o[n] = __builtin_amdgcn_mfma_f32_16x16x32_bf16(af, bv, o[n], 0, 0, 0);
            }
        }
        __syncthreads();
    }

    if (nsplit == 1) {
#pragma unroll
        for (int n = 0; n < 8; ++n) {
            int h = n * 16 + lo;
#pragma unroll
            for (int r = 0; r < 4; ++r) {
                int row = qrow_base + r;
                out[((size_t)b * T + row) * HD + h] = o[n][r] / lrow[r];
            }
        }
    } else {
        const size_t slot = (size_t)(b * 32 + qt) * 4 + s;
        unsigned short* po = part_o + slot * (QB * HD);
#pragma unroll
        for (int n = 0; n < 8; ++n) {
            int h = n * 16 + lo;
#pragma unroll
            for (int r = 0; r < 4; ++r)
                po[(w * 16 + hi * 4 + r) * HD + h] = f2bf(o[n][r]);
        }
        if (lo == 0) {
            float* pm = part_ml + slot * (QB * 2);
#pragma unroll
            for (int r = 0; r < 4; ++r) {
                pm[(w * 16 + hi * 4 + r) * 2 + 0] = mrow[r];
                pm[(w * 16 + hi * 4 + r) * 2 + 1] = lrow[r];
            }
        }
    }
}

// ---------------------------------------------------------------------------
// Kernel 3: combine split partials (bf16 partials)
// ---------------------------------------------------------------------------
__global__ __launch_bounds__(256) void attn_combine(
    const unsigned short* __restrict__ part_o, const float* __restrict__ part_ml,
    float* __restrict__ out)
{
    const int qt = 8 + blockIdx.x;     // 8..31
    const int b  = blockIdx.y;
    const int ns = qt / 8 + 1;         // 2..4
    const int tid = threadIdx.x;
    const int row = tid >> 2;          // 0..63
    const int c0  = (tid & 3) * 32;
    const size_t slot0 = (size_t)(b * 32 + qt) * 4;

    float mi[4], li[4];
    float m = -1e30f;
#pragma unroll 4
    for (int i = 0; i < ns; ++i) {
        mi[i] = part_ml[(slot0 + i) * (QB * 2) + row * 2 + 0];
        li[i] = part_ml[(slot0 + i) * (QB * 2) + row * 2 + 1];
        m = fmaxf(m, mi[i]);
    }
    float L = 0.0f, f[4];
#pragma unroll 4
    for (int i = 0; i < ns; ++i) {
        f[i] = exp2f(mi[i] - m);
        L += li[i] * f[i];
    }
    const float inv = 1.0f / L;

    float acc[32];
#pragma unroll
    for (int k = 0; k < 32; ++k) acc[k] = 0.0f;
#pragma unroll 4
    for (int i = 0; i < ns; ++i) {
        const short8* src = (const short8*)(part_o + (slot0 + i) * (QB * HD) + row * HD + c0);
#pragma unroll
        for (int k = 0; k < 4; ++k) {
            short8 v = src[k];
#pragma unroll
            for (int e = 0; e < 8; ++e)
                acc[k * 8 + e] += f[i] * bf2f((unsigned short)v[e]);
        }
    }
    float4* dst = (float4*)(out + ((size_t)b * T + qt * QB + row) * HD + c0);
#pragma unroll
    for (int k = 0; k < 8; ++k)
        dst[k] = make_float4(acc[k * 4 + 0] * inv, acc[k * 4 + 1] * inv,
                             acc[k * 4 + 2] * inv, acc[k * 4 + 3] * inv);
}

// ---------------------------------------------------------------------------
extern "C" void kernel_launch(void* const* d_in, const int* in_sizes, int n_in,
                              void* d_out, int out_size, void* d_ws, size_t ws_size,
                              hipStream_t stream)
{
    const float* x  = (const float*)d_in[0];
    const float* Wq = (const float*)d_in[1];
    const float* Wk = (const float*)d_in[2];
    const float* Wv = (const float*)d_in[3];
    float* out = (float*)d_out;

    // ws layout (bytes) — offsets kept from prior rounds (part_o oversized)
    const size_t off_Wb = 0;
    const size_t off_Q  = off_Wb + (size_t)NW * EMB * 2;        // 1.5 MB
    const size_t off_K  = off_Q  + (size_t)M * HD * 2;
    const size_t off_V  = off_K  + (size_t)M * HD * 2;
    const size_t off_po = off_V  + (size_t)M * HD * 2;
    const size_t off_ml = off_po + (size_t)1024 * QB * HD * 4;
    const size_t total  = off_ml + (size_t)1024 * QB * 2 * 4;

    char* ws = (char*)d_ws;
    unsigned short* Wb  = (unsigned short*)(ws + off_Wb);
    unsigned short* Qb  = (unsigned short*)(ws + off_Q);
    unsigned short* Kb  = (unsigned short*)(ws + off_K);
    unsigned short* VtG = (unsigned short*)(ws + off_V);
    unsigned short* part_o = (unsigned short*)(ws + off_po);
    float* part_ml = (float*)(ws + off_ml);

    const int use_split = (ws_size >= total) ? 1 : 0;

    conv_w<<<dim3((NW * EMB) / (256 * 8)), 256, 0, stream>>>(Wq, Wk, Wv, Wb);
    qkv_proj<<<dim3(512), 256, 0, stream>>>(x, Wb, Qb, Kb, VtG);
    attn_fwd<<<dim3(use_split ? 80 : 32, B), 256, 0, stream>>>(
        Qb, Kb, VtG, out, part_o, part_ml, use_split);
    if (use_split)
        attn_combine<<<dim3(24, B), 256, 0, stream>>>(part_o, part_ml, out);
}

// Round 20
// 99.324 us; speedup vs baseline: 1.0231x; 1.0231x over previous
//
#include <hip/hip_runtime.h>
#include <hip/hip_bf16.h>
#include <stdint.h>

// Problem constants
constexpr int B    = 8;
constexpr int T    = 2048;
constexpr int EMB  = 2048;
constexpr int HD   = 128;
constexpr int M    = B * T;        // 16384 rows for projection GEMM
constexpr int NW   = 3 * HD;       // 384 fused output cols (Q|K|V)

typedef __attribute__((ext_vector_type(8))) short short8;
typedef __attribute__((ext_vector_type(4))) float f32x4;

__device__ inline unsigned short f2bf(float f) {
    union { float f; unsigned int u; } v; v.f = f;
    unsigned int x = v.u;
    unsigned int r = (x + 0x7FFFu + ((x >> 16) & 1u)) >> 16;   // RNE
    return (unsigned short)r;
}

__device__ inline float bf2f(unsigned short s) {
    union { unsigned int u; float f; } v; v.u = ((unsigned int)s) << 16;
    return v.f;
}

__device__ inline unsigned int cvt_pk_bf16(float a, float b) {
    unsigned int r;
    asm volatile("v_cvt_pk_bf16_f32 %0, %1, %2" : "=v"(r) : "v"(a), "v"(b));
    return r;   // lo = bf16(a), hi = bf16(b)
}

// ---------------------------------------------------------------------------
// Kernel 0: convert Wq|Wk|Wv fp32 -> bf16 into Wb[384][2048]
// ---------------------------------------------------------------------------
__global__ __launch_bounds__(256) void conv_w(
    const float* __restrict__ Wq, const float* __restrict__ Wk, const float* __restrict__ Wv,
    unsigned short* __restrict__ Wb)
{
    int base = (blockIdx.x * 256 + threadIdx.x) * 8;   // < 384*2048
    int row = base >> 11, col = base & 2047;
    const float* src;
    if (row < 128)      src = Wq + (size_t)row * EMB + col;
    else if (row < 256) src = Wk + (size_t)(row - 128) * EMB + col;
    else                src = Wv + (size_t)(row - 256) * EMB + col;
    float4 a = *(const float4*)src;
    float4 b = *(const float4*)(src + 4);
    short8 sv;
    sv[0] = f2bf(a.x); sv[1] = f2bf(a.y); sv[2] = f2bf(a.z); sv[3] = f2bf(a.w);
    sv[4] = f2bf(b.x); sv[5] = f2bf(b.y); sv[6] = f2bf(b.z); sv[7] = f2bf(b.w);
    *(short8*)(Wb + base) = sv;
}

// ---------------------------------------------------------------------------
// Kernel 1: fused QKV projection — FINAL (best measured, R18: ~75.7us).
// BN=192 2-balanced-blocks mapping, reg-staged B + XOR ds_write, A cvt_pk,
// staggered K walk, sched_barrier-pinned load-before-compute.
// ---------------------------------------------------------------------------
constexpr int PBM = 64;
constexpr int PBN = 192;
constexpr int PBK = 64;
constexpr int PNT = EMB / PBK;   // 32

__global__ __launch_bounds__(256, 2) void qkv_proj(
    const float* __restrict__ x, const unsigned short* __restrict__ Wb,
    unsigned short* __restrict__ Qb, unsigned short* __restrict__ Kb,
    unsigned short* __restrict__ VtG)
{
    __shared__ unsigned short Ab[2][PBM * PBK];   // 2 x 8 KB
    __shared__ unsigned short Bb[2][PBN * PBK];   // 2 x 24 KB  (64 KB total)

    const int d   = blockIdx.x;          // 0..511
    const int xcd = d & 7;
    const int g   = d >> 3;              // 0..63
    const int mt  = xcd * 32 + (g >> 1); // 0..255
    const int ns  = g & 1;               // N-half
    const int m0  = mt * PBM;
    const int n0  = ns * PBN;
    const int phase = g & 31;            // staggered K start per in-XCD block

    const int tid  = threadIdx.x;
    const int lane = tid & 63;
    const int w    = tid >> 6;           // 0..3
    const int lo   = lane & 15;
    const int hi   = lane >> 4;

    const int ar = tid >> 2;             // 0..63
    const int s0 = (tid & 3) * 2;        // first 8-float seg (0,2,4,6)
    const float* asrc = x + (size_t)(m0 + ar) * EMB + s0 * 8;

    f32x4 acc[4][3];
#pragma unroll
    for (int i = 0; i < 4; ++i)
#pragma unroll
        for (int j = 0; j < 3; ++j) acc[i][j] = (f32x4)0.0f;

    short8 breg[6];
    float4 a0, a1, a2, a3;

    auto loadTile = [&](int k0) {
#pragma unroll
        for (int it = 0; it < 6; ++it) {
            int c = it * 256 + tid;
            int row = c >> 3, seg = c & 7;
            breg[it] = *(const short8*)(Wb + (size_t)(n0 + row) * EMB + k0 + seg * 8);
        }
        a0 = *(const float4*)(asrc + k0);
        a1 = *(const float4*)(asrc + k0 + 4);
        a2 = *(const float4*)(asrc + k0 + 8);
        a3 = *(const float4*)(asrc + k0 + 12);
    };
    auto writeTile = [&](int buf) {
#pragma unroll
        for (int it = 0; it < 6; ++it) {
            int c = it * 256 + tid;
            int row = c >> 3, seg = c & 7;
            *(short8*)&Bb[buf][row * PBK + (seg ^ (row & 7)) * 8] = breg[it];
        }
        uint4 p0, p1;
        p0.x = cvt_pk_bf16(a0.x, a0.y);  p0.y = cvt_pk_bf16(a0.z, a0.w);
        p0.z = cvt_pk_bf16(a1.x, a1.y);  p0.w = cvt_pk_bf16(a1.z, a1.w);
        p1.x = cvt_pk_bf16(a2.x, a2.y);  p1.y = cvt_pk_bf16(a2.z, a2.w);
        p1.z = cvt_pk_bf16(a3.x, a3.y);  p1.w = cvt_pk_bf16(a3.z, a3.w);
        *(uint4*)&Ab[buf][ar * PBK + ((s0    ) ^ (ar & 7)) * 8] = p0;
        *(uint4*)&Ab[buf][ar * PBK + ((s0 + 1) ^ (ar & 7)) * 8] = p1;
    };
    auto compute = [&](int buf) {
#pragma unroll
        for (int kk = 0; kk < 2; ++kk) {
            short8 af[4], bf[3];
            const int cseg = kk * 4 + hi;
#pragma unroll
            for (int i = 0; i < 4; ++i) {
                int R = i * 16 + lo;
                af[i] = *(const short8*)&Ab[buf][R * PBK + (cseg ^ (R & 7)) * 8];
            }
#pragma unroll
            for (int j = 0; j < 3; ++j) {
                int n = w * 48 + j * 16 + lo;     // local col in 192
                bf[j] = *(const short8*)&Bb[buf][n * PBK + (cseg ^ (n & 7)) * 8];
            }
#pragma unroll
            for (int i = 0; i < 4; ++i)
#pragma unroll
                for (int j = 0; j < 3; ++j)
                    acc[i][j] = __builtin_amdgcn_mfma_f32_16x16x32_bf16(af[i], bf[j], acc[i][j], 0, 0, 0);
        }
    };

    loadTile(phase * PBK);
    writeTile(0);
    __syncthreads();

#pragma unroll 1
    for (int t = 0; t < PNT; ++t) {
        const int buf = t & 1;
        if (t + 1 < PNT) {
            const int tnext = (phase + t + 1) & 31;   // circular K walk
            loadTile(tnext * PBK);                // VMEM issued FIRST
            __builtin_amdgcn_sched_barrier(0);
        }
        compute(buf);
        if (t + 1 < PNT) {
            __builtin_amdgcn_sched_barrier(0);
            writeTile(buf ^ 1);
            __syncthreads();
        }
    }

    // epilogue. C layout: row = hi*4+r, col = lo.
    const int b = m0 >> 11;
#pragma unroll
    for (int i = 0; i < 4; ++i) {
        int mrow0 = m0 + i * 16 + hi * 4;
#pragma unroll
        for (int j = 0; j < 3; ++j) {
            int colbase = n0 + w * 48 + j * 16 + lo;   // 0..383
            if (colbase < 128) {               // Q
#pragma unroll
                for (int r = 0; r < 4; ++r)
                    Qb[(size_t)(mrow0 + r) * HD + colbase] = f2bf(acc[i][j][r]);
            } else if (colbase < 256) {        // K
#pragma unroll
                for (int r = 0; r < 4; ++r)
                    Kb[(size_t)(mrow0 + r) * HD + (colbase - 128)] = f2bf(acc[i][j][r]);
            } else {                           // V -> transposed [B][HD][T]
                int h = colbase - 256;
                int tloc = mrow0 - b * T;
                ushort4 pv;
                pv.x = f2bf(acc[i][j][0]); pv.y = f2bf(acc[i][j][1]);
                pv.z = f2bf(acc[i][j][2]); pv.w = f2bf(acc[i][j][3]);
                *(ushort4*)(VtG + ((size_t)(b * HD + h)) * T + tloc) = pv;
            }
        }
    }
}

// ---------------------------------------------------------------------------
// Kernel 2: causal flash attention with KV-split (FINAL: R15 structure,
// bf16 split-partials).
// ---------------------------------------------------------------------------
constexpr int QB = 64;
constexpr int KB = 64;
constexpr int STILES = 8;   // kv tiles per split block

__global__ __launch_bounds__(256) void attn_fwd(
    const unsigned short* __restrict__ Qb,
    const unsigned short* __restrict__ Kb,
    const unsigned short* __restrict__ VtG,
    float* __restrict__ out,
    unsigned short* __restrict__ part_o, float* __restrict__ part_ml,
    int use_split)
{
    const int b  = blockIdx.y;
    int bx = blockIdx.x;
    int qt, s, nsplit;
    if (use_split) {
        if (bx < 8)       { qt = bx;               s = 0; }
        else if (bx < 24) { qt = 8  + (bx - 8) / 2;  s = (bx - 8) & 1; }
        else if (bx < 48) { qt = 16 + (bx - 24) / 3; s = (bx - 24) % 3; }
        else              { qt = 24 + (bx - 48) / 4; s = (bx - 48) & 3; }
        nsplit = qt / 8 + 1;
    } else {
        qt = bx; s = 0; nsplit = 1;
    }
    const int q0 = qt * QB;
    int t0 = s * STILES;
    int t1 = t0 + STILES; if (t1 > qt + 1) t1 = qt + 1;

    const int tid  = threadIdx.x;
    const int lane = tid & 63;
    const int w    = tid >> 6;
    const int lo   = lane & 15;
    const int hi   = lane >> 4;

    __shared__ unsigned short Ks[KB][HD + 8];    // stride 272B == 4 banks mod 32
    __shared__ unsigned short Vt[HD][KB + 16];   // stride 160B == 8 banks mod 32
    __shared__ unsigned short Ps[QB][KB + 8];

    short8 qf[4];
    {
        int row = q0 + w * 16 + lo;
        const unsigned short* qp = Qb + ((size_t)b * T + row) * HD + hi * 8;
#pragma unroll
        for (int ks = 0; ks < 4; ++ks) qf[ks] = *(const short8*)(qp + ks * 32);
    }

    float mrow[4], lrow[4];
    f32x4 o[8];
#pragma unroll
    for (int r = 0; r < 4; ++r) { mrow[r] = -1e30f; lrow[r] = 0.0f; }
#pragma unroll
    for (int n = 0; n < 8; ++n) o[n] = (f32x4)0.0f;

    const float scale2 = 0.022097086912079608f * 1.4426950408889634f;
    const int qrow_base = q0 + w * 16 + hi * 4;

    for (int t = t0; t < t1; ++t) {
        const int kv0 = t * KB;
#pragma unroll
        for (int it = 0; it < 4; ++it) {
            int c = tid + it * 256;
            int row = c >> 4, c8 = (c & 15) * 8;
            *(short8*)&Ks[row][c8] =
                *(const short8*)(Kb + ((size_t)b * T + kv0 + row) * HD + c8);
        }
#pragma unroll
        for (int it = 0; it < 4; ++it) {
            int c = tid + it * 256;
            int row = c >> 3, c8 = (c & 7) * 8;
            *(short8*)&Vt[row][c8] =
                *(const short8*)(VtG + (size_t)(b * HD + row) * T + kv0 + c8);
        }
        __syncthreads();

        f32x4 sa[4];
#pragma unroll
        for (int j = 0; j < 4; ++j) sa[j] = (f32x4)0.0f;
#pragma unroll
        for (int ks = 0; ks < 4; ++ks) {
#pragma unroll
            for (int j = 0; j < 4; ++j) {
                short8 bf = *(const short8*)&Ks[j * 16 + lo][ks * 32 + hi * 8];
                sa[j] = __builtin_amdgcn_mfma_f32_16x16x32_bf16(qf[ks], bf, sa[j], 0, 0, 0);
            }
        }

        const bool diag = (t == qt);
        float alpha[4];
#pragma unroll
        for (int r = 0; r < 4; ++r) {
            const int qrow = qrow_base + r;
            float rm = -1e30f;
#pragma unroll
            for (int j = 0; j < 4; ++j) {
                float v = sa[j][r] * scale2;
                if (diag) {
                    int kv = kv0 + j * 16 + lo;
                    v = (kv <= qrow) ? v : -1e30f;
                }
                sa[j][r] = v;
                rm = fmaxf(rm, v);
            }
            rm = fmaxf(rm, __shfl_xor(rm, 1));
            rm = fmaxf(rm, __shfl_xor(rm, 2));
            rm = fmaxf(rm, __shfl_xor(rm, 4));
            rm = fmaxf(rm, __shfl_xor(rm, 8));
            float mn = fmaxf(mrow[r], rm);
            alpha[r] = exp2f(mrow[r] - mn);
            mrow[r] = mn;
            float ls = 0.0f;
#pragma unroll
            for (int j = 0; j < 4; ++j) {
                float p = exp2f(sa[j][r] - mn);
                sa[j][r] = p;
                ls += p;
            }
            ls += __shfl_xor(ls, 1);
            ls += __shfl_xor(ls, 2);
            ls += __shfl_xor(ls, 4);
            ls += __shfl_xor(ls, 8);
            lrow[r] = lrow[r] * alpha[r] + ls;
        }
#pragma unroll
        for (int n = 0; n < 8; ++n)
#pragma unroll
            for (int r = 0; r < 4; ++r) o[n][r] *= alpha[r];

#pragma unroll
        for (int r = 0; r < 4; ++r)
#pragma unroll
            for (int j = 0; j < 4; ++j)
                Ps[w * 16 + hi * 4 + r][j * 16 + lo] = f2bf(sa[j][r]);
        __syncthreads();

#pragma unroll
        for (int ks = 0; ks < 2; ++ks) {
            short8 af = *(const short8*)&Ps[w * 16 + lo][ks * 32 + hi * 8];
#pragma unroll
            for (int n = 0; n < 8; ++n) {
                short8 bv = *(const short8*)&Vt[n * 16 + lo][ks * 32 + hi * 8];
                o[n] = __builtin_amdgcn_mfma_f32_16x16x32_bf16(af, bv, o[n], 0, 0, 0);
            }
        }
        __syncthreads();
    }

    if (nsplit == 1) {
#pragma unroll
        for (int n = 0; n < 8; ++n) {
            int h = n * 16 + lo;
#pragma unroll
            for (int r = 0; r < 4; ++r) {
                int row = qrow_base + r;
                out[((size_t)b * T + row) * HD + h] = o[n][r] / lrow[r];
            }
        }
    } else {
        const size_t slot = (size_t)(b * 32 + qt) * 4 + s;
        unsigned short* po = part_o + slot * (QB * HD);
#pragma unroll
        for (int n = 0; n < 8; ++n) {
            int h = n * 16 + lo;
#pragma unroll
            for (int r = 0; r < 4; ++r)
                po[(w * 16 + hi * 4 + r) * HD + h] = f2bf(o[n][r]);
        }
        if (lo == 0) {
            float* pm = part_ml + slot * (QB * 2);
#pragma unroll
            for (int r = 0; r < 4; ++r) {
                pm[(w * 16 + hi * 4 + r) * 2 + 0] = mrow[r];
                pm[(w * 16 + hi * 4 + r) * 2 + 1] = lrow[r];
            }
        }
    }
}

// ---------------------------------------------------------------------------
// Kernel 3: combine split partials (bf16 partials)
// ---------------------------------------------------------------------------
__global__ __launch_bounds__(256) void attn_combine(
    const unsigned short* __restrict__ part_o, const float* __restrict__ part_ml,
    float* __restrict__ out)
{
    const int qt = 8 + blockIdx.x;     // 8..31
    const int b  = blockIdx.y;
    const int ns = qt / 8 + 1;         // 2..4
    const int tid = threadIdx.x;
    const int row = tid >> 2;          // 0..63
    const int c0  = (tid & 3) * 32;
    const size_t slot0 = (size_t)(b * 32 + qt) * 4;

    float mi[4], li[4];
    float m = -1e30f;
#pragma unroll 4
    for (int i = 0; i < ns; ++i) {
        mi[i] = part_ml[(slot0 + i) * (QB * 2) + row * 2 + 0];
        li[i] = part_ml[(slot0 + i) * (QB * 2) + row * 2 + 1];
        m = fmaxf(m, mi[i]);
    }
    float L = 0.0f, f[4];
#pragma unroll 4
    for (int i = 0; i < ns; ++i) {
        f[i] = exp2f(mi[i] - m);
        L += li[i] * f[i];
    }
    const float inv = 1.0f / L;

    float acc[32];
#pragma unroll
    for (int k = 0; k < 32; ++k) acc[k] = 0.0f;
#pragma unroll 4
    for (int i = 0; i < ns; ++i) {
        const short8* src = (const short8*)(part_o + (slot0 + i) * (QB * HD) + row * HD + c0);
#pragma unroll
        for (int k = 0; k < 4; ++k) {
            short8 v = src[k];
#pragma unroll
            for (int e = 0; e < 8; ++e)
                acc[k * 8 + e] += f[i] * bf2f((unsigned short)v[e]);
        }
    }
    float4* dst = (float4*)(out + ((size_t)b * T + qt * QB + row) * HD + c0);
#pragma unroll
    for (int k = 0; k < 8; ++k)
        dst[k] = make_float4(acc[k * 4 + 0] * inv, acc[k * 4 + 1] * inv,
                             acc[k * 4 + 2] * inv, acc[k * 4 + 3] * inv);
}

// ---------------------------------------------------------------------------
extern "C" void kernel_launch(void* const* d_in, const int* in_sizes, int n_in,
                              void* d_out, int out_size, void* d_ws, size_t ws_size,
                              hipStream_t stream)
{
    const float* x  = (const float*)d_in[0];
    const float* Wq = (const float*)d_in[1];
    const float* Wk = (const float*)d_in[2];
    const float* Wv = (const float*)d_in[3];
    float* out = (float*)d_out;

    // ws layout (bytes) — offsets kept from prior rounds (part_o oversized)
    const size_t off_Wb = 0;
    const size_t off_Q  = off_Wb + (size_t)NW * EMB * 2;        // 1.5 MB
    const size_t off_K  = off_Q  + (size_t)M * HD * 2;
    const size_t off_V  = off_K  + (size_t)M * HD * 2;
    const size_t off_po = off_V  + (size_t)M * HD * 2;
    const size_t off_ml = off_po + (size_t)1024 * QB * HD * 4;
    const size_t total  = off_ml + (size_t)1024 * QB * 2 * 4;

    char* ws = (char*)d_ws;
    unsigned short* Wb  = (unsigned short*)(ws + off_Wb);
    unsigned short* Qb  = (unsigned short*)(ws + off_Q);
    unsigned short* Kb  = (unsigned short*)(ws + off_K);
    unsigned short* VtG = (unsigned short*)(ws + off_V);
    unsigned short* part_o = (unsigned short*)(ws + off_po);
    float* part_ml = (float*)(ws + off_ml);

    const int use_split = (ws_size >= total) ? 1 : 0;

    conv_w<<<dim3((NW * EMB) / (256 * 8)), 256, 0, stream>>>(Wq, Wk, Wv, Wb);
    qkv_proj<<<dim3(512), 256, 0, stream>>>(x, Wb, Qb, Kb, VtG);
    attn_fwd<<<dim3(use_split ? 80 : 32, B), 256, 0, stream>>>(
        Qb, Kb, VtG, out, part_o, part_ml, use_split);
    if (use_split)
        attn_combine<<<dim3(24, B), 256, 0, stream>>>(part_o, part_ml, out);
}